// Round 2
// baseline (115.468 us; speedup 1.0000x reference)
//
#include <hip/hip_runtime.h>

// GNNInteractionNetwork: out[b,i] = sum_j m(r2_ij) * (r2_ij+eps^2)^-1.5 * (pos_j - pos_i)
// Key insight: the edge MLP m(.) is a scalar piecewise-linear function of r2 only.
// Kernel 1 tabulates m on a uniform grid (d_ws); kernel 2 does the O(N^2) pair pass
// with linear interpolation + exact fp32 physics term. Exact MLP fallback for r2
// beyond table range (rare tail) keeps correctness unconditional.

#define HID    64
#define NPTS   1024
#define NBATCH 2
#define TSCALE 512.0f
#define TINV   (1.0f/512.0f)
#define TNTAB  (72*512 + 2)   // covers r2 in [0,72], +1 entry for interp, +1 slack

__device__ __forceinline__ float mlp_eval(float r2,
    const float* __restrict__ w1, const float* __restrict__ b1,
    const float* __restrict__ W2, const float* __restrict__ b2,
    const float* __restrict__ w3, float b3v)
{
    float acc[HID];
#pragma unroll
    for (int k = 0; k < HID; ++k) acc[k] = b2[k];
#pragma unroll
    for (int h = 0; h < HID; ++h) {
        // layer 1: h1 = relu(r2*w1[h] + b1[h]); weights are wave-uniform -> s_load
        float h1 = fmaxf(fmaf(r2, w1[h], b1[h]), 0.0f);
        const float* __restrict__ wrow = W2 + h * HID;   // W2[h][k], row-major
#pragma unroll
        for (int k = 0; k < HID; ++k) acc[k] = fmaf(h1, wrow[k], acc[k]);
    }
    float m = b3v;
#pragma unroll
    for (int k = 0; k < HID; ++k) m = fmaf(fmaxf(acc[k], 0.0f), w3[k], m);
    return m;
}

// Cold-path exact eval (shared single copy, keeps hot loop I$ small)
__device__ __attribute__((noinline)) float mlp_eval_cold(float r2,
    const float* w1, const float* b1, const float* W2, const float* b2,
    const float* w3, float b3v)
{
    return mlp_eval(r2, w1, b1, W2, b2, w3, b3v);
}

__global__ __launch_bounds__(256) void build_tab_kernel(
    const float* __restrict__ w1, const float* __restrict__ b1,
    const float* __restrict__ W2, const float* __restrict__ b2,
    const float* __restrict__ w3, const float* __restrict__ b3,
    float* __restrict__ T)
{
    int t = blockIdx.x * 256 + threadIdx.x;
    if (t < TNTAB) T[t] = mlp_eval((float)t * TINV, w1, b1, W2, b2, w3, b3[0]);
}

template <bool USE_TAB>
__global__ __launch_bounds__(256) void forces_kernel(
    const float* __restrict__ pos, const float* __restrict__ epsp,
    const float* __restrict__ w1, const float* __restrict__ b1,
    const float* __restrict__ W2, const float* __restrict__ b2,
    const float* __restrict__ w3, const float* __restrict__ b3p,
    const float* __restrict__ T, float* __restrict__ out)
{
    const int bi = blockIdx.x;          // 0 .. NBATCH*NPTS-1
    const int b  = bi >> 10;
    const int i  = bi & (NPTS - 1);
    const float* __restrict__ pb = pos + (size_t)b * NPTS * 3;

    // uniform across block -> scalar loads
    const float pix = pb[3*i+0], piy = pb[3*i+1], piz = pb[3*i+2];
    const float eps = epsp[0];
    const float e2  = eps * eps;
    const float b3v = b3p[0];

    float ax = 0.0f, ay = 0.0f, az = 0.0f;

#pragma unroll
    for (int c = 0; c < NPTS / 256; ++c) {
        const int j = (c << 8) + (int)threadIdx.x;
        const float* __restrict__ pj = pb + 3 * j;
        const float dx = pj[0] - pix;
        const float dy = pj[1] - piy;
        const float dz = pj[2] - piz;
        const float r2 = fmaf(dx, dx, fmaf(dy, dy, dz * dz));
        if (j != i) {
            float m;
            if (USE_TAB) {
                const float tp  = r2 * TSCALE;
                const int   idx = (int)tp;
                if (idx <= TNTAB - 2) {
                    const float f0 = T[idx];
                    const float f1 = T[idx + 1];
                    m = fmaf(f1 - f0, tp - (float)idx, f0);
                } else {
                    m = mlp_eval_cold(r2, w1, b1, W2, b2, w3, b3v); // rare tail
                }
            } else {
                m = mlp_eval_cold(r2, w1, b1, W2, b2, w3, b3v);
            }
            const float rr   = r2 + e2;
            const float rs   = rsqrtf(rr);
            const float phys = rs * rs * rs;     // (r2+eps^2)^-1.5, exact fp32
            const float cf   = m * phys;
            ax = fmaf(cf, dx, ax);
            ay = fmaf(cf, dy, ay);
            az = fmaf(cf, dz, az);
        }
    }

    // wave (64-lane) shuffle reduce
#pragma unroll
    for (int off = 32; off > 0; off >>= 1) {
        ax += __shfl_down(ax, off);
        ay += __shfl_down(ay, off);
        az += __shfl_down(az, off);
    }

    __shared__ float red[4][3];
    const int lane = threadIdx.x & 63;
    const int w    = threadIdx.x >> 6;
    if (lane == 0) { red[w][0] = ax; red[w][1] = ay; red[w][2] = az; }
    __syncthreads();
    if (threadIdx.x == 0) {
        out[3 * bi + 0] = red[0][0] + red[1][0] + red[2][0] + red[3][0];
        out[3 * bi + 1] = red[0][1] + red[1][1] + red[2][1] + red[3][1];
        out[3 * bi + 2] = red[0][2] + red[1][2] + red[2][2] + red[3][2];
    }
}

extern "C" void kernel_launch(void* const* d_in, const int* in_sizes, int n_in,
                              void* d_out, int out_size, void* d_ws, size_t ws_size,
                              hipStream_t stream)
{
    const float* pos = (const float*)d_in[0];
    const float* eps = (const float*)d_in[1];
    const float* w1  = (const float*)d_in[2];
    const float* b1  = (const float*)d_in[3];
    const float* W2  = (const float*)d_in[4];
    const float* b2  = (const float*)d_in[5];
    const float* w3  = (const float*)d_in[6];
    const float* b3  = (const float*)d_in[7];
    float* out = (float*)d_out;
    float* T   = (float*)d_ws;

    const bool use_tab = (ws_size >= (size_t)TNTAB * sizeof(float));

    if (use_tab) {
        build_tab_kernel<<<dim3((TNTAB + 255) / 256), dim3(256), 0, stream>>>(
            w1, b1, W2, b2, w3, b3, T);
        forces_kernel<true><<<dim3(NBATCH * NPTS), dim3(256), 0, stream>>>(
            pos, eps, w1, b1, W2, b2, w3, b3, T, out);
    } else {
        // no workspace: exact (slow) path, still correct
        forces_kernel<false><<<dim3(NBATCH * NPTS), dim3(256), 0, stream>>>(
            pos, eps, w1, b1, W2, b2, w3, b3, (const float*)nullptr, out);
    }
}

// Round 3
// 82.691 us; speedup vs baseline: 1.3964x; 1.3964x over previous
//
#include <hip/hip_runtime.h>

// GNNInteractionNetwork: out[b,i] = sum_j m(r2_ij) * (r2_ij+eps^2)^-1.5 * (pos_j - pos_i)
// m(.) is a scalar piecewise-linear function of r2 -> tabulate once per launch.
// R2 fix: wave-cooperative build (R1's per-thread acc[64] spilled: VGPR=36, 43us).
// Table stored as float2 {f_i, f_{i+1}}: one 8B gather per pair. Delta=1/64,
// 72*64 entries = 37KB (~L1-resident). Exact MLP fallback for r2 > 72 (P~1e-7).

#define HID    64
#define NPTS   1024
#define NBATCH 2
#define TSCALE 64.0f
#define TINV   (1.0f/64.0f)
#define TNTAB  (72*64 + 2)   // f-grid points; interp valid for idx <= TNTAB-2

// Exact per-thread MLP eval — cold path only (tail r2 beyond table).
__device__ __attribute__((noinline)) float mlp_eval_cold(float r2,
    const float* w1, const float* b1, const float* W2, const float* b2,
    const float* w3, float b3v)
{
    float acc[HID];
#pragma unroll
    for (int k = 0; k < HID; ++k) acc[k] = b2[k];
    for (int h = 0; h < HID; ++h) {
        float h1 = fmaxf(fmaf(r2, w1[h], b1[h]), 0.0f);
        const float* wrow = W2 + h * HID;
#pragma unroll
        for (int k = 0; k < HID; ++k) acc[k] = fmaf(h1, wrow[k], acc[k]);
    }
    float m = b3v;
#pragma unroll
    for (int k = 0; k < HID; ++k) m = fmaf(fmaxf(acc[k], 0.0f), w3[k], m);
    return m;
}

// One wave per table entry. Lane h does layer-1 neuron h; layer-2 via wave
// broadcast (shfl) + coalesced W2-row loads; butterfly reduce for the output.
// Per-thread live state ~4 floats -> no spill (R1 post-mortem fix).
__global__ __launch_bounds__(256) void build_tab_kernel(
    const float* __restrict__ w1, const float* __restrict__ b1,
    const float* __restrict__ W2, const float* __restrict__ b2,
    const float* __restrict__ w3, const float* __restrict__ b3,
    float* __restrict__ Tp)   // float pairs: Tp[2e]=f_e (x), Tp[2e-1]=f_e (y of e-1)
{
    const int gw   = (int)((blockIdx.x * 256 + threadIdx.x) >> 6); // wave id = entry
    const int lane = (int)(threadIdx.x & 63);
    if (gw >= TNTAB) return;                 // wave-uniform exit

    const float r2 = (float)gw * TINV;
    // layer 1: lane h -> h1_h  (coalesced w1/b1 loads, L1-hot)
    const float h1 = fmaxf(fmaf(r2, w1[lane], b1[lane]), 0.0f);

    // layer 2: lane k accumulates sum_h h1_h * W2[h][k]
    float acc = b2[lane];
#pragma unroll
    for (int h = 0; h < HID; ++h) {
        const float h1h = __shfl(h1, h);               // broadcast
        acc = fmaf(h1h, W2[h * HID + lane], acc);      // 256B coalesced row read
    }

    // layer 3 + wave reduce
    float o = fmaxf(acc, 0.0f) * w3[lane];
#pragma unroll
    for (int off = 32; off; off >>= 1) o += __shfl_xor(o, off);

    const float f = o + b3[0];
    if (lane == 0)               Tp[2 * gw]     = f;   // x of entry gw
    else if (lane == 1 && gw)    Tp[2 * gw - 1] = f;   // y of entry gw-1
}

template <bool USE_TAB>
__global__ __launch_bounds__(256) void forces_kernel(
    const float* __restrict__ pos, const float* __restrict__ epsp,
    const float* __restrict__ w1, const float* __restrict__ b1,
    const float* __restrict__ W2, const float* __restrict__ b2,
    const float* __restrict__ w3, const float* __restrict__ b3p,
    const float2* __restrict__ T2, float* __restrict__ out)
{
    const int bi = blockIdx.x;          // 0 .. NBATCH*NPTS-1
    const int b  = bi >> 10;
    const int i  = bi & (NPTS - 1);
    const float* __restrict__ pb = pos + (size_t)b * NPTS * 3;

    // uniform across block -> scalar loads
    const float pix = pb[3*i+0], piy = pb[3*i+1], piz = pb[3*i+2];
    const float eps = epsp[0];
    const float e2  = eps * eps;
    const float b3v = b3p[0];

    float ax = 0.0f, ay = 0.0f, az = 0.0f;

#pragma unroll
    for (int c = 0; c < NPTS / 256; ++c) {
        const int j = (c << 8) + (int)threadIdx.x;
        const float* __restrict__ pj = pb + 3 * j;
        const float dx = pj[0] - pix;
        const float dy = pj[1] - piy;
        const float dz = pj[2] - piz;
        const float r2 = fmaf(dx, dx, fmaf(dy, dy, dz * dz));
        if (j != i) {
            float m;
            const float tp  = r2 * TSCALE;
            const int   idx = (int)tp;
            if (USE_TAB && idx <= TNTAB - 2) {
                const float2 t = T2[idx];              // one 8B gather
                m = fmaf(t.y - t.x, tp - (float)idx, t.x);
            } else {
                m = mlp_eval_cold(r2, w1, b1, W2, b2, w3, b3v); // rare tail / no-ws
            }
            const float rr   = r2 + e2;
            const float rs   = rsqrtf(rr);
            const float phys = rs * rs * rs;           // (r2+eps^2)^-1.5 exact fp32
            const float cf   = m * phys;
            ax = fmaf(cf, dx, ax);
            ay = fmaf(cf, dy, ay);
            az = fmaf(cf, dz, az);
        }
    }

    // 64-lane butterfly, then tiny cross-wave LDS reduce
#pragma unroll
    for (int off = 32; off > 0; off >>= 1) {
        ax += __shfl_down(ax, off);
        ay += __shfl_down(ay, off);
        az += __shfl_down(az, off);
    }

    __shared__ float red[4][3];
    const int lane = (int)(threadIdx.x & 63);
    const int w    = (int)(threadIdx.x >> 6);
    if (lane == 0) { red[w][0] = ax; red[w][1] = ay; red[w][2] = az; }
    __syncthreads();
    if (threadIdx.x == 0) {
        out[3 * bi + 0] = red[0][0] + red[1][0] + red[2][0] + red[3][0];
        out[3 * bi + 1] = red[0][1] + red[1][1] + red[2][1] + red[3][1];
        out[3 * bi + 2] = red[0][2] + red[1][2] + red[2][2] + red[3][2];
    }
}

extern "C" void kernel_launch(void* const* d_in, const int* in_sizes, int n_in,
                              void* d_out, int out_size, void* d_ws, size_t ws_size,
                              hipStream_t stream)
{
    const float* pos = (const float*)d_in[0];
    const float* eps = (const float*)d_in[1];
    const float* w1  = (const float*)d_in[2];
    const float* b1  = (const float*)d_in[3];
    const float* W2  = (const float*)d_in[4];
    const float* b2  = (const float*)d_in[5];
    const float* w3  = (const float*)d_in[6];
    const float* b3  = (const float*)d_in[7];
    float* out = (float*)d_out;

    const bool use_tab = (ws_size >= (size_t)TNTAB * sizeof(float2));

    if (use_tab) {
        // one wave per entry -> TNTAB waves
        const int nblocks = (TNTAB * 64 + 255) / 256;
        build_tab_kernel<<<dim3(nblocks), dim3(256), 0, stream>>>(
            w1, b1, W2, b2, w3, b3, (float*)d_ws);
        forces_kernel<true><<<dim3(NBATCH * NPTS), dim3(256), 0, stream>>>(
            pos, eps, w1, b1, W2, b2, w3, b3, (const float2*)d_ws, out);
    } else {
        forces_kernel<false><<<dim3(NBATCH * NPTS), dim3(256), 0, stream>>>(
            pos, eps, w1, b1, W2, b2, w3, b3, (const float2*)nullptr, out);
    }
}